// Round 1
// baseline (1462.217 us; speedup 1.0000x reference)
//
#include <hip/hip_runtime.h>
#include <hip/hip_bf16.h>
#include <math.h>

#define NH 8
#define DKk 256
#define DVv 512
#define Bn 2
#define Tn 2048
#define HID 2048
#define EPSf 1e-5f

typedef __bf16 bf16x8 __attribute__((ext_vector_type(8)));
typedef float f32x4 __attribute__((ext_vector_type(4)));
using bf16 = __hip_bfloat16;
typedef unsigned short ushort_t;

__device__ __forceinline__ void gload_lds16(const void* g, void* lds_base) {
  __builtin_amdgcn_global_load_lds(
      (const __attribute__((address_space(1))) void*)g,
      (__attribute__((address_space(3))) void*)lds_base, 16, 0, 0);
}

__device__ __forceinline__ ushort_t f2bf_raw(float f) {
  bf16 h = __float2bfloat16(f);
  return *reinterpret_cast<ushort_t*>(&h);
}

// ---------------- fp32 -> bf16 elementwise (vectorized x4) ----------------
__global__ void k_f32_to_bf16(const float4* __restrict__ in, ushort4* __restrict__ out, int n4) {
  int i = blockIdx.x * blockDim.x + threadIdx.x;
  if (i >= n4) return;
  float4 v = in[i];
  ushort4 o;
  o.x = f2bf_raw(v.x); o.y = f2bf_raw(v.y); o.z = f2bf_raw(v.z); o.w = f2bf_raw(v.w);
  out[i] = o;
}

// ---------------- W (K,N) fp32 -> WT (N,K) bf16 ----------------
__global__ void k_transpose_w(const float* __restrict__ W, bf16* __restrict__ WT, int K, int N) {
  __shared__ float t[32][33];
  int n0 = blockIdx.x * 32, k0 = blockIdx.y * 32;
  int tx = threadIdx.x, ty = threadIdx.y;
#pragma unroll
  for (int i = 0; i < 4; i++)
    t[ty + i * 8][tx] = W[(size_t)(k0 + ty + i * 8) * N + n0 + tx];
  __syncthreads();
#pragma unroll
  for (int i = 0; i < 4; i++)
    WT[(size_t)(n0 + ty + i * 8) * K + k0 + tx] = __float2bfloat16(t[tx][ty + i * 8]);
}

// ---------------- v (b,t,h,dv) bf16 -> vT (b,h,dv,t) bf16 ----------------
__global__ void k_transpose_v(const bf16* __restrict__ v, bf16* __restrict__ vT) {
  __shared__ bf16 t[32][33];
  int b = blockIdx.z >> 3, h = blockIdx.z & 7;
  int t0 = blockIdx.x * 32, d0 = blockIdx.y * 32;
  int tx = threadIdx.x, ty = threadIdx.y;
#pragma unroll
  for (int i = 0; i < 4; i++)
    t[ty + i * 8][tx] = v[((size_t)(b * Tn + t0 + ty + i * 8) * NH + h) * DVv + d0 + tx];
  __syncthreads();
#pragma unroll
  for (int i = 0; i < 4; i++)
    vT[((size_t)(b * NH + h) * DVv + d0 + ty + i * 8) * Tn + t0 + tx] = t[tx][ty + i * 8];
}

// ---------------- RoPE in-place on bf16 (b,t,h,dk), scale folded ----------------
__global__ void k_rope(bf16* __restrict__ x, float scale) {
  int tid = blockIdx.x * 256 + threadIdx.x;
  int i = tid & 127;
  int h = (tid >> 7) & 7;
  int t = (tid >> 10) & (Tn - 1);
  int b = tid >> 21;
  // inv_freq = 10000^(-i/128) = exp2(-i/128 * log2(10000))
  float inv = exp2f(-(float)i * (13.287712379549449f / 128.0f));
  float ang = (float)t * inv;
  float s, c;
  sincosf(ang, &s, &c);
  size_t base = ((size_t)(b * Tn + t) * NH + h) * DKk + i;
  float x1 = __bfloat162float(x[base]);
  float x2 = __bfloat162float(x[base + 128]);
  x[base]       = __float2bfloat16((x1 * c - x2 * s) * scale);
  x[base + 128] = __float2bfloat16((x2 * c + x1 * s) * scale);
}

// ---------------- m97-style GEMM: C(M,N) = A(M,K) @ BT(N,K)^T ----------------
// A, BT row-major bf16. 128x128 block tile, BK=32, 4 waves (2x2), wave tile 64x64.
template <bool OUT_BF16>
__global__ __launch_bounds__(256) void k_gemm(const bf16* __restrict__ A, const bf16* __restrict__ BT,
                                              void* __restrict__ Cout, int M, int N, int K) {
  __shared__ __align__(16) bf16 a_lds[128 * 32];
  __shared__ __align__(16) bf16 b_lds[128 * 32];
  const int tid = threadIdx.x;
  const int l = tid & 63;
  const int w = tid >> 6;
  const int wr = w >> 1, wc = w & 1;
  const int m0 = blockIdx.y * 128, n0 = blockIdx.x * 128;
  const int quad = l >> 4, c16 = l & 15;

  // staging: per wave 2 instrs per tile; each instr = 16 rows x 64B (1KB)
  const int lrow = l >> 2;         // 0..15
  const int loff = (l & 3) * 16;   // bytes within row
  const char* aG0 = (const char*)(A + (size_t)(m0 + w * 32 + lrow) * K) + loff;
  const char* aG1 = (const char*)(A + (size_t)(m0 + w * 32 + 16 + lrow) * K) + loff;
  const char* bG0 = (const char*)(BT + (size_t)(n0 + w * 32 + lrow) * K) + loff;
  const char* bG1 = (const char*)(BT + (size_t)(n0 + w * 32 + 16 + lrow) * K) + loff;
  char* aL0 = (char*)a_lds + w * 2048;
  char* aL1 = (char*)a_lds + w * 2048 + 1024;
  char* bL0 = (char*)b_lds + w * 2048;
  char* bL1 = (char*)b_lds + w * 2048 + 1024;

  f32x4 acc[4][4];
  const f32x4 fz = {0.f, 0.f, 0.f, 0.f};
#pragma unroll
  for (int r = 0; r < 4; r++)
#pragma unroll
    for (int c = 0; c < 4; c++) acc[r][c] = fz;

  for (int k0 = 0; k0 < K; k0 += 32) {
    __syncthreads();
    size_t kb = (size_t)k0 * 2;
    gload_lds16(aG0 + kb, aL0);
    gload_lds16(aG1 + kb, aL1);
    gload_lds16(bG0 + kb, bL0);
    gload_lds16(bG1 + kb, bL1);
    __syncthreads();
    bf16x8 af[4], bfv[4];
#pragma unroll
    for (int r = 0; r < 4; r++)
      af[r] = *(const bf16x8*)(a_lds + (wr * 64 + r * 16 + c16) * 32 + quad * 8);
#pragma unroll
    for (int c = 0; c < 4; c++)
      bfv[c] = *(const bf16x8*)(b_lds + (wc * 64 + c * 16 + c16) * 32 + quad * 8);
#pragma unroll
    for (int r = 0; r < 4; r++)
#pragma unroll
      for (int c = 0; c < 4; c++)
        acc[r][c] = __builtin_amdgcn_mfma_f32_16x16x32_bf16(af[r], bfv[c], acc[r][c], 0, 0, 0);
  }

#pragma unroll
  for (int r = 0; r < 4; r++)
#pragma unroll
    for (int c = 0; c < 4; c++)
#pragma unroll
      for (int rr = 0; rr < 4; rr++) {
        int m = m0 + wr * 64 + r * 16 + quad * 4 + rr;
        int n = n0 + wc * 64 + c * 16 + c16;
        float val = acc[r][c][rr];
        if (OUT_BF16) ((bf16*)Cout)[(size_t)m * N + n] = __float2bfloat16(val);
        else          ((float*)Cout)[(size_t)m * N + n] = val;
      }
}

// ---------------- Retention: per (b,h), 64-row Q tile, 32-col KV steps ----------------
// q,k: (b,t,h,dk) bf16 (q pre-scaled). vT: (b,h,dv,t) bf16. g: (b,t,h,dv) bf16.
// X out: (b,t,h,dv) bf16 = RMSNorm(o)*gnw * silu(g)
__global__ __launch_bounds__(256) void k_retention(const bf16* __restrict__ q, const bf16* __restrict__ k,
                                                   const bf16* __restrict__ vT, const bf16* __restrict__ g,
                                                   const float* __restrict__ gnw, bf16* __restrict__ X) {
  __shared__ __align__(16) char smem[53248];
  bf16* k_lds = (bf16*)smem;             // [32][256] = 16KB
  bf16* v_lds = (bf16*)(smem + 16384);   // [512][32] = 32KB
  bf16* p_lds = (bf16*)(smem + 49152);   // [64][32]  = 4KB
  bf16* g_lds = (bf16*)smem;             // [64][128] = 16KB (epilogue reuse)
  bf16* o_lds = (bf16*)(smem + 16384);   // [64][128] = 16KB (epilogue reuse)

  const int tid = threadIdx.x;
  const int l = tid & 63, w = tid >> 6;
  const int quad = l >> 4, c16 = l & 15;
  const int b = blockIdx.z, h = blockIdx.y;
  const int qt = gridDim.x - 1 - blockIdx.x;  // longest blocks first
  const int q0 = qt * 64;

  // q fragments for wave's 16 rows: A[m=c16][dk]
  bf16x8 qf[8];
  {
    const bf16* qrow = q + ((size_t)(b * Tn + q0 + w * 16 + c16) * NH + h) * DKk + quad * 8;
#pragma unroll
    for (int c = 0; c < 8; c++) qf[c] = *(const bf16x8*)(qrow + c * 32);
  }

  const float log2g = log2f(1.0f - exp2f(-5.0f - (float)h));

  f32x4 acc[32];
  const f32x4 fz = {0.f, 0.f, 0.f, 0.f};
#pragma unroll
  for (int n = 0; n < 32; n++) acc[n] = fz;

  const int ktmax = (q0 + 63) >> 5;  // inclusive
  const float Dcut = 30.0f / (-log2g);
  int kt0 = (int)fmaxf(0.0f, floorf(((float)(q0 - 31) - Dcut) * (1.0f / 32.0f)));

  for (int kt = kt0; kt <= ktmax; kt++) {
    __syncthreads();
    {  // stage k tile (16KB): 4 instrs/wave, 2 rows each
      int roww = l >> 5;
      int offb = (l & 31) * 16;
#pragma unroll
      for (int i = 0; i < 4; i++) {
        int instr = w * 4 + i;
        int row = instr * 2 + roww;
        const char* gp = (const char*)(k + ((size_t)(b * Tn + kt * 32 + row) * NH + h) * DKk) + offb;
        gload_lds16(gp, (char*)k_lds + instr * 1024);
      }
      // stage vT tile (32KB): 8 instrs/wave, 16 rows each
      int rowv = l >> 2;
      int offv = (l & 3) * 16;
#pragma unroll
      for (int i = 0; i < 8; i++) {
        int instr = w * 8 + i;
        int row = instr * 16 + rowv;  // dv
        const char* gp = (const char*)(vT + ((size_t)(b * NH + h) * DVv + row) * Tn + kt * 32) + offv;
        gload_lds16(gp, (char*)v_lds + instr * 1024);
      }
    }
    __syncthreads();

    // S = q @ k^T : wave's 16 rows x 32 j
    f32x4 sacc0 = fz, sacc1 = fz;
#pragma unroll
    for (int c = 0; c < 8; c++) {
      bf16x8 b0 = *(const bf16x8*)(k_lds + (size_t)c16 * 256 + c * 32 + quad * 8);
      bf16x8 b1 = *(const bf16x8*)(k_lds + (size_t)(16 + c16) * 256 + c * 32 + quad * 8);
      sacc0 = __builtin_amdgcn_mfma_f32_16x16x32_bf16(qf[c], b0, sacc0, 0, 0, 0);
      sacc1 = __builtin_amdgcn_mfma_f32_16x16x32_bf16(qf[c], b1, sacc1, 0, 0, 0);
    }

    // decay + causal mask -> P (bf16) via LDS (C-layout -> A-layout transform)
#pragma unroll
    for (int tt = 0; tt < 2; tt++) {
      f32x4 s = tt ? sacc1 : sacc0;
#pragma unroll
      for (int r = 0; r < 4; r++) {
        int ig = q0 + w * 16 + quad * 4 + r;
        int jg = kt * 32 + tt * 16 + c16;
        int d = ig - jg;
        float val = (d >= 0) ? s[r] * exp2f(log2g * (float)d) : 0.0f;
        p_lds[(w * 16 + quad * 4 + r) * 32 + tt * 16 + c16] = __float2bfloat16(val);
      }
    }
    __syncthreads();

    // O += P @ V  (B from vT: B[n=dv][k=j])
    bf16x8 pa = *(const bf16x8*)(p_lds + (w * 16 + c16) * 32 + quad * 8);
#pragma unroll
    for (int n = 0; n < 32; n++) {
      bf16x8 bv = *(const bf16x8*)(v_lds + (n * 16 + c16) * 32 + quad * 8);
      acc[n] = __builtin_amdgcn_mfma_f32_16x16x32_bf16(pa, bv, acc[n], 0, 0, 0);
    }
  }

  // RMS per row (reduce across 16 lanes of same quad)
  float ss[4];
#pragma unroll
  for (int r = 0; r < 4; r++) {
    float s = 0.f;
#pragma unroll
    for (int n = 0; n < 32; n++) { float v = acc[n][r]; s += v * v; }
    s += __shfl_xor(s, 1);
    s += __shfl_xor(s, 2);
    s += __shfl_xor(s, 4);
    s += __shfl_xor(s, 8);
    ss[r] = rsqrtf(s * (1.0f / DVv) + EPSf);
  }

  // epilogue: per 128-col chunk, stage g, gate, coalesced store
  for (int ch = 0; ch < 4; ch++) {
    __syncthreads();
    {  // stage g chunk (16KB): 4 instrs/wave, 4 rows each
      int rowg = l >> 4;
      int offg = (l & 15) * 16;
#pragma unroll
      for (int i = 0; i < 4; i++) {
        int instr = w * 4 + i;
        int row = instr * 4 + rowg;
        const char* gp = (const char*)(g + ((size_t)(b * Tn + q0 + row) * NH + h) * DVv + ch * 128) + offg;
        gload_lds16(gp, (char*)g_lds + instr * 1024);
      }
    }
    __syncthreads();
#pragma unroll
    for (int n8 = 0; n8 < 8; n8++) {
      int n = ch * 8 + n8;
      int col = n * 16 + c16;
      float gw = gnw[col];
#pragma unroll
      for (int r = 0; r < 4; r++) {
        int rl = w * 16 + quad * 4 + r;
        float gv = __bfloat162float(g_lds[rl * 128 + n8 * 16 + c16]);
        float gate = gv / (1.0f + expf(-gv));
        float val = acc[n][r] * ss[r] * gw * gate;
        o_lds[rl * 128 + n8 * 16 + c16] = __float2bfloat16(val);
      }
    }
    __syncthreads();
#pragma unroll
    for (int j = 0; j < 4; j++) {
      int cid = tid + j * 256;       // 0..1023 16B chunks
      int row = cid >> 4;
      int cp = (cid & 15) * 8;       // element offset
      uint4 vv = *(const uint4*)(o_lds + row * 128 + cp);
      *(uint4*)(X + ((size_t)(b * Tn + q0 + row) * NH + h) * DVv + ch * 128 + cp) = vv;
    }
  }
}

extern "C" void kernel_launch(void* const* d_in, const int* in_sizes, int n_in,
                              void* d_out, int out_size, void* d_ws, size_t ws_size,
                              hipStream_t stream) {
  const float* hs  = (const float*)d_in[0];
  const float* Wq  = (const float*)d_in[1];
  const float* Wk  = (const float*)d_in[2];
  const float* Wv  = (const float*)d_in[3];
  const float* Wg  = (const float*)d_in[4];
  const float* Wo  = (const float*)d_in[5];
  const float* gnw = (const float*)d_in[6];
  float* out = (float*)d_out;
  char* ws = (char*)d_ws;

  // region A (dead after GEMMs): hsb | WqT | WkT | WvT | WgT   -> reused by vT, WoT
  bf16* hsb = (bf16*)(ws);                    // 16,777,216 B
  bf16* WqT = (bf16*)(ws + 16777216);         //  8,388,608 B
  bf16* WkT = (bf16*)(ws + 25165824);         //  8,388,608 B
  bf16* WvT = (bf16*)(ws + 33554432);         // 16,777,216 B
  bf16* WgT = (bf16*)(ws + 50331648);         // 16,777,216 B
  bf16* vTb = (bf16*)(ws);                    // alias hsb+WqT+WkT (33,554,432 B)
  bf16* WoT = (bf16*)(ws + 33554432);         // alias WvT (16,777,216 B)
  // region B
  bf16* qb = (bf16*)(ws + 67108864);          // 16,777,216 B
  bf16* kb = (bf16*)(ws + 83886080);          // 16,777,216 B
  bf16* vb = (bf16*)(ws + 100663296);         // 33,554,432 B
  bf16* gb = (bf16*)(ws + 134217728);         // 33,554,432 B  (total 160 MB)
  bf16* Xb = vb;                               // alias v (dead after vT transpose)

  dim3 tb(32, 8);

  // 1. hs -> bf16
  k_f32_to_bf16<<<8192, 256, 0, stream>>>((const float4*)hs, (ushort4*)hsb, 2097152);
  // 2. weight transposes (fp32 -> bf16^T)
  k_transpose_w<<<dim3(HID / 32, HID / 32), tb, 0, stream>>>(Wq, WqT, HID, HID);
  k_transpose_w<<<dim3(HID / 32, HID / 32), tb, 0, stream>>>(Wk, WkT, HID, HID);
  k_transpose_w<<<dim3(NH * DVv / 32, HID / 32), tb, 0, stream>>>(Wv, WvT, HID, NH * DVv);
  k_transpose_w<<<dim3(NH * DVv / 32, HID / 32), tb, 0, stream>>>(Wg, WgT, HID, NH * DVv);
  // 3. projections (bf16 out)
  k_gemm<true><<<dim3(16, 32), 256, 0, stream>>>(hsb, WqT, qb, 4096, 2048, 2048);
  k_gemm<true><<<dim3(16, 32), 256, 0, stream>>>(hsb, WkT, kb, 4096, 2048, 2048);
  k_gemm<true><<<dim3(32, 32), 256, 0, stream>>>(hsb, WvT, vb, 4096, 4096, 2048);
  k_gemm<true><<<dim3(32, 32), 256, 0, stream>>>(hsb, WgT, gb, 4096, 4096, 2048);
  // 4. RoPE (scale folded into q)
  k_rope<<<16384, 256, 0, stream>>>(qb, 0.0625f);
  k_rope<<<16384, 256, 0, stream>>>(kb, 1.0f);
  // 5. v -> vT, Wo -> WoT (into dead region A)
  k_transpose_v<<<dim3(Tn / 32, DVv / 32, Bn * NH), tb, 0, stream>>>(vb, vTb);
  k_transpose_w<<<dim3(HID / 32, NH * DVv / 32), tb, 0, stream>>>(Wo, WoT, NH * DVv, HID);
  // 6. retention + RMSNorm + gate -> X (aliases v)
  k_retention<<<dim3(Tn / 64, NH, Bn), 256, 0, stream>>>(qb, kb, vTb, gb, gnw, Xb);
  // 7. output projection (fp32 out)
  k_gemm<false><<<dim3(16, 32), 256, 0, stream>>>(Xb, WoT, out, 4096, 2048, 4096);
}

// Round 2
// 873.013 us; speedup vs baseline: 1.6749x; 1.6749x over previous
//
#include <hip/hip_runtime.h>
#include <hip/hip_bf16.h>
#include <math.h>

#define NH 8
#define DKk 256
#define DVv 512
#define Bn 2
#define Tn 2048
#define HID 2048
#define EPSf 1e-5f

typedef __bf16 bf16x8 __attribute__((ext_vector_type(8)));
typedef float f32x4 __attribute__((ext_vector_type(4)));
using bf16 = __hip_bfloat16;
typedef unsigned short ushort_t;

__device__ __forceinline__ void gload_lds16(const void* g, void* lds_base) {
  __builtin_amdgcn_global_load_lds(
      (const __attribute__((address_space(1))) void*)g,
      (__attribute__((address_space(3))) void*)lds_base, 16, 0, 0);
}

__device__ __forceinline__ ushort_t f2bf_raw(float f) {
  bf16 h = __float2bfloat16(f);
  return *reinterpret_cast<ushort_t*>(&h);
}

// ---------------- fp32 -> bf16 elementwise (vectorized x4) ----------------
__global__ void k_f32_to_bf16(const float4* __restrict__ in, ushort4* __restrict__ out, int n4) {
  int i = blockIdx.x * blockDim.x + threadIdx.x;
  if (i >= n4) return;
  float4 v = in[i];
  ushort4 o;
  o.x = f2bf_raw(v.x); o.y = f2bf_raw(v.y); o.z = f2bf_raw(v.z); o.w = f2bf_raw(v.w);
  out[i] = o;
}

// ---------------- W (K,N) fp32 -> WT (N,K) bf16 ----------------
__global__ void k_transpose_w(const float* __restrict__ W, bf16* __restrict__ WT, int K, int N) {
  __shared__ float t[32][33];
  int n0 = blockIdx.x * 32, k0 = blockIdx.y * 32;
  int tx = threadIdx.x, ty = threadIdx.y;
#pragma unroll
  for (int i = 0; i < 4; i++)
    t[ty + i * 8][tx] = W[(size_t)(k0 + ty + i * 8) * N + n0 + tx];
  __syncthreads();
#pragma unroll
  for (int i = 0; i < 4; i++)
    WT[(size_t)(n0 + ty + i * 8) * K + k0 + tx] = __float2bfloat16(t[tx][ty + i * 8]);
}

// ---------------- v (b,t,h,dv) bf16 -> vT (b,h,dv,t) bf16 ----------------
__global__ void k_transpose_v(const bf16* __restrict__ v, bf16* __restrict__ vT) {
  __shared__ bf16 t[32][33];
  int b = blockIdx.z >> 3, h = blockIdx.z & 7;
  int t0 = blockIdx.x * 32, d0 = blockIdx.y * 32;
  int tx = threadIdx.x, ty = threadIdx.y;
#pragma unroll
  for (int i = 0; i < 4; i++)
    t[ty + i * 8][tx] = v[((size_t)(b * Tn + t0 + ty + i * 8) * NH + h) * DVv + d0 + tx];
  __syncthreads();
#pragma unroll
  for (int i = 0; i < 4; i++)
    vT[((size_t)(b * NH + h) * DVv + d0 + ty + i * 8) * Tn + t0 + tx] = t[tx][ty + i * 8];
}

// ---------------- RoPE in-place on bf16 (b,t,h,dk), scale folded ----------------
__global__ void k_rope(bf16* __restrict__ x, float scale) {
  int tid = blockIdx.x * 256 + threadIdx.x;
  int i = tid & 127;
  int h = (tid >> 7) & 7;
  int t = (tid >> 10) & (Tn - 1);
  int b = tid >> 21;
  float inv = exp2f(-(float)i * (13.287712379549449f / 128.0f));
  float ang = (float)t * inv;
  float s, c;
  sincosf(ang, &s, &c);
  size_t base = ((size_t)(b * Tn + t) * NH + h) * DKk + i;
  float x1 = __bfloat162float(x[base]);
  float x2 = __bfloat162float(x[base + 128]);
  x[base]       = __float2bfloat16((x1 * c - x2 * s) * scale);
  x[base + 128] = __float2bfloat16((x2 * c + x1 * s) * scale);
}

// ---------------- m97-style GEMM: C(M,N) = A(M,K) @ BT(N,K)^T ----------------
template <bool OUT_BF16>
__global__ __launch_bounds__(256) void k_gemm(const bf16* __restrict__ A, const bf16* __restrict__ BT,
                                              void* __restrict__ Cout, int M, int N, int K) {
  __shared__ __align__(16) bf16 a_lds[128 * 32];
  __shared__ __align__(16) bf16 b_lds[128 * 32];
  const int tid = threadIdx.x;
  const int l = tid & 63;
  const int w = tid >> 6;
  const int wr = w >> 1, wc = w & 1;
  const int m0 = blockIdx.y * 128, n0 = blockIdx.x * 128;
  const int quad = l >> 4, c16 = l & 15;

  const int lrow = l >> 2;
  const int loff = (l & 3) * 16;
  const char* aG0 = (const char*)(A + (size_t)(m0 + w * 32 + lrow) * K) + loff;
  const char* aG1 = (const char*)(A + (size_t)(m0 + w * 32 + 16 + lrow) * K) + loff;
  const char* bG0 = (const char*)(BT + (size_t)(n0 + w * 32 + lrow) * K) + loff;
  const char* bG1 = (const char*)(BT + (size_t)(n0 + w * 32 + 16 + lrow) * K) + loff;
  char* aL0 = (char*)a_lds + w * 2048;
  char* aL1 = (char*)a_lds + w * 2048 + 1024;
  char* bL0 = (char*)b_lds + w * 2048;
  char* bL1 = (char*)b_lds + w * 2048 + 1024;

  f32x4 acc[4][4];
  const f32x4 fz = {0.f, 0.f, 0.f, 0.f};
#pragma unroll
  for (int r = 0; r < 4; r++)
#pragma unroll
    for (int c = 0; c < 4; c++) acc[r][c] = fz;

  for (int k0 = 0; k0 < K; k0 += 32) {
    __syncthreads();
    size_t kb = (size_t)k0 * 2;
    gload_lds16(aG0 + kb, aL0);
    gload_lds16(aG1 + kb, aL1);
    gload_lds16(bG0 + kb, bL0);
    gload_lds16(bG1 + kb, bL1);
    __syncthreads();
    bf16x8 af[4], bfv[4];
#pragma unroll
    for (int r = 0; r < 4; r++)
      af[r] = *(const bf16x8*)(a_lds + (wr * 64 + r * 16 + c16) * 32 + quad * 8);
#pragma unroll
    for (int c = 0; c < 4; c++)
      bfv[c] = *(const bf16x8*)(b_lds + (wc * 64 + c * 16 + c16) * 32 + quad * 8);
#pragma unroll
    for (int r = 0; r < 4; r++)
#pragma unroll
      for (int c = 0; c < 4; c++)
        acc[r][c] = __builtin_amdgcn_mfma_f32_16x16x32_bf16(af[r], bfv[c], acc[r][c], 0, 0, 0);
  }

#pragma unroll
  for (int r = 0; r < 4; r++)
#pragma unroll
    for (int c = 0; c < 4; c++)
#pragma unroll
      for (int rr = 0; rr < 4; rr++) {
        int m = m0 + wr * 64 + r * 16 + quad * 4 + rr;
        int n = n0 + wc * 64 + c * 16 + c16;
        float val = acc[r][c][rr];
        if (OUT_BF16) ((bf16*)Cout)[(size_t)m * N + n] = __float2bfloat16(val);
        else          ((float*)Cout)[(size_t)m * N + n] = val;
      }
}

// ---------------- Retention: per (b,h), 32-row Q tile, 2x2 wave split ----------------
// Each wave: 16 rows x 256 cols -> acc[16] (64 VGPRs). No spills.
// q,k: (b,t,h,dk) bf16 (q pre-scaled). vT: (b,h,dv,t) bf16. g: (b,t,h,dv) bf16.
__global__ __launch_bounds__(256, 2) void k_retention(const bf16* __restrict__ q, const bf16* __restrict__ k,
                                                      const bf16* __restrict__ vT, const bf16* __restrict__ g,
                                                      const float* __restrict__ gnw, bf16* __restrict__ X) {
  __shared__ __align__(16) char smem[51456];
  bf16* k_lds = (bf16*)smem;               // [32 j][256 dk] = 16KB, 16B-chunk XOR swizzle
  bf16* v_lds = (bf16*)(smem + 16384);     // [512 dv][32 j] = 32KB
  bf16* p_lds = (bf16*)(smem + 49152);     // [32][32] = 2KB
  float* red  = (float*)(smem + 51200);    // [32][2] partial row sums = 256B
  bf16* g_lds = (bf16*)smem;               // [32][256] epilogue reuse (aliases k_lds)
  bf16* o_lds = (bf16*)(smem + 16384);     // [32][256] epilogue reuse (aliases v_lds)

  const int tid = threadIdx.x;
  const int l = tid & 63, w = tid >> 6;
  const int wr = w >> 1, wc = w & 1;
  const int quad = l >> 4, c16 = l & 15;
  const int b = blockIdx.z, h = blockIdx.y;
  const int qt = gridDim.x - 1 - blockIdx.x;  // longest blocks first
  const int q0 = qt * 32;

  // q fragments: wave's 16 rows (q0 + wr*16 + c16), full DK. A[m=c16][k=quad*8+j]
  bf16x8 qf[8];
  {
    const bf16* qrow = q + ((size_t)(b * Tn + q0 + wr * 16 + c16) * NH + h) * DKk + quad * 8;
#pragma unroll
    for (int c = 0; c < 8; c++) qf[c] = *(const bf16x8*)(qrow + c * 32);
  }

  const float log2g = log2f(1.0f - exp2f(-5.0f - (float)h));

  f32x4 acc[16];
  const f32x4 fz = {0.f, 0.f, 0.f, 0.f};
#pragma unroll
  for (int n = 0; n < 16; n++) acc[n] = fz;

  const int ktmax = (q0 + 31) >> 5;  // inclusive (== qt)
  const float Dcut = 30.0f / (-log2g);
  int kt0 = (int)fmaxf(0.0f, floorf(((float)(q0 - 31) - Dcut) * (1.0f / 32.0f)));

  for (int kt = kt0; kt <= ktmax; kt++) {
    __syncthreads();
    {  // stage k tile [32 j][512B], XOR-swizzled at 16B granularity: slot s holds chunk s^(j&7)
      int jrel = (w * 4) * 2 + 0;  // base; per-instr below
#pragma unroll
      for (int i = 0; i < 4; i++) {
        int instr = w * 4 + i;
        int j = instr * 2 + (l >> 5);
        int chunk_g = (l & 31) ^ (j & 7);
        const char* gp = (const char*)(k + ((size_t)(b * Tn + kt * 32 + j) * NH + h) * DKk) + chunk_g * 16;
        gload_lds16(gp, (char*)k_lds + instr * 1024);
      }
      (void)jrel;
      // stage vT tile [512 dv][64B]: 8 instrs/wave, 16 rows each
#pragma unroll
      for (int i = 0; i < 8; i++) {
        int instr = w * 8 + i;
        int dv = instr * 16 + (l >> 2);
        const char* gp = (const char*)(vT + ((size_t)(b * NH + h) * DVv + dv) * Tn + kt * 32) + (l & 3) * 16;
        gload_lds16(gp, (char*)v_lds + instr * 1024);
      }
    }
    __syncthreads();

    // S tile 16x16 per wave: rows q0+wr*16+*, cols kt*32+wc*16+*
    f32x4 sacc = fz;
#pragma unroll
    for (int c = 0; c < 8; c++) {
      // B[n=c16][k=c*32+quad*8+..]: row (wc*16+c16), chunk (c*4+quad) ^ swizzle
      const char* kp = (const char*)k_lds + (wc * 16 + c16) * 512 + (((c * 4 + quad) ^ (c16 & 7)) * 16);
      bf16x8 bfrag = *(const bf16x8*)kp;
      sacc = __builtin_amdgcn_mfma_f32_16x16x32_bf16(qf[c], bfrag, sacc, 0, 0, 0);
    }

    // decay + causal mask -> P (bf16) in LDS (C-layout -> A-layout transform)
#pragma unroll
    for (int r = 0; r < 4; r++) {
      int ig = q0 + wr * 16 + quad * 4 + r;
      int jg = kt * 32 + wc * 16 + c16;
      int d = ig - jg;
      float val = (d >= 0) ? sacc[r] * exp2f(log2g * (float)d) : 0.0f;
      p_lds[(wr * 16 + quad * 4 + r) * 32 + wc * 16 + c16] = __float2bfloat16(val);
    }
    __syncthreads();

    // O += P @ V : A = P rows wr*16.., B = vT rows wc*256..
    bf16x8 pa = *(const bf16x8*)(p_lds + (wr * 16 + c16) * 32 + quad * 8);
#pragma unroll
    for (int n = 0; n < 16; n++) {
      bf16x8 bv = *(const bf16x8*)(v_lds + (wc * 256 + n * 16 + c16) * 32 + quad * 8);
      acc[n] = __builtin_amdgcn_mfma_f32_16x16x32_bf16(pa, bv, acc[n], 0, 0, 0);
    }
  }

  // RMS: partial sum over this wave's 256 cols, reduce across c16 lanes, combine wc halves via LDS
  float ss[4];
  {
    float part[4];
#pragma unroll
    for (int r = 0; r < 4; r++) {
      float s = 0.f;
#pragma unroll
      for (int n = 0; n < 16; n++) { float v = acc[n][r]; s += v * v; }
      s += __shfl_xor(s, 1);
      s += __shfl_xor(s, 2);
      s += __shfl_xor(s, 4);
      s += __shfl_xor(s, 8);
      part[r] = s;
    }
    if (c16 == 0) {
#pragma unroll
      for (int r = 0; r < 4; r++)
        red[(wr * 16 + quad * 4 + r) * 2 + wc] = part[r];
    }
    __syncthreads();
#pragma unroll
    for (int r = 0; r < 4; r++) {
      int row = wr * 16 + quad * 4 + r;
      float tot = red[row * 2] + red[row * 2 + 1];
      ss[r] = rsqrtf(tot * (1.0f / DVv) + EPSf);
    }
  }

  // epilogue: two 256-col halves; stage g, gate, coalesced store
  for (int ch = 0; ch < 2; ch++) {
    __syncthreads();
    {  // stage g [32 rows][512B of half ch]: 4 instrs/wave, 2 rows each
#pragma unroll
      for (int i = 0; i < 4; i++) {
        int instr = w * 4 + i;
        int row = instr * 2 + (l >> 5);
        const char* gp = (const char*)(g + ((size_t)(b * Tn + q0 + row) * NH + h) * DVv + ch * 256) + (l & 31) * 16;
        gload_lds16(gp, (char*)g_lds + instr * 1024);
      }
    }
    __syncthreads();
    if (wc == ch) {
#pragma unroll
      for (int n = 0; n < 16; n++) {
        int col = n * 16 + c16;
        float gw = gnw[ch * 256 + col];
#pragma unroll
        for (int r = 0; r < 4; r++) {
          int rowl = wr * 16 + quad * 4 + r;
          float gv = __bfloat162float(g_lds[rowl * 256 + col]);
          float gate = gv / (1.0f + expf(-gv));
          float val = acc[n][r] * ss[r] * gw * gate;
          o_lds[rowl * 256 + col] = __float2bfloat16(val);
        }
      }
    }
    __syncthreads();
#pragma unroll
    for (int j = 0; j < 4; j++) {
      int cid = tid + j * 256;       // 1024 x 16B chunks = [32 rows][32 chunks]
      int row = cid >> 5;
      int cp = (cid & 31) * 8;
      uint4 vv = *(const uint4*)(o_lds + row * 256 + cp);
      *(uint4*)(X + ((size_t)(b * Tn + q0 + row) * NH + h) * DVv + ch * 256 + cp) = vv;
    }
  }
}

extern "C" void kernel_launch(void* const* d_in, const int* in_sizes, int n_in,
                              void* d_out, int out_size, void* d_ws, size_t ws_size,
                              hipStream_t stream) {
  const float* hs  = (const float*)d_in[0];
  const float* Wq  = (const float*)d_in[1];
  const float* Wk  = (const float*)d_in[2];
  const float* Wv  = (const float*)d_in[3];
  const float* Wg  = (const float*)d_in[4];
  const float* Wo  = (const float*)d_in[5];
  const float* gnw = (const float*)d_in[6];
  float* out = (float*)d_out;
  char* ws = (char*)d_ws;

  bf16* hsb = (bf16*)(ws);                    // 16 MB
  bf16* WqT = (bf16*)(ws + 16777216);         //  8 MB
  bf16* WkT = (bf16*)(ws + 25165824);         //  8 MB
  bf16* WvT = (bf16*)(ws + 33554432);         // 16 MB
  bf16* WgT = (bf16*)(ws + 50331648);         // 16 MB
  bf16* vTb = (bf16*)(ws);                    // alias (32 MB)
  bf16* WoT = (bf16*)(ws + 33554432);         // alias WvT (16 MB)
  bf16* qb = (bf16*)(ws + 67108864);          // 16 MB
  bf16* kb = (bf16*)(ws + 83886080);          // 16 MB
  bf16* vb = (bf16*)(ws + 100663296);         // 32 MB
  bf16* gb = (bf16*)(ws + 134217728);         // 32 MB
  bf16* Xb = vb;                               // alias v (dead after vT transpose)

  dim3 tb(32, 8);

  k_f32_to_bf16<<<8192, 256, 0, stream>>>((const float4*)hs, (ushort4*)hsb, 2097152);
  k_transpose_w<<<dim3(HID / 32, HID / 32), tb, 0, stream>>>(Wq, WqT, HID, HID);
  k_transpose_w<<<dim3(HID / 32, HID / 32), tb, 0, stream>>>(Wk, WkT, HID, HID);
  k_transpose_w<<<dim3(NH * DVv / 32, HID / 32), tb, 0, stream>>>(Wv, WvT, HID, NH * DVv);
  k_transpose_w<<<dim3(NH * DVv / 32, HID / 32), tb, 0, stream>>>(Wg, WgT, HID, NH * DVv);
  k_gemm<true><<<dim3(16, 32), 256, 0, stream>>>(hsb, WqT, qb, 4096, 2048, 2048);
  k_gemm<true><<<dim3(16, 32), 256, 0, stream>>>(hsb, WkT, kb, 4096, 2048, 2048);
  k_gemm<true><<<dim3(32, 32), 256, 0, stream>>>(hsb, WvT, vb, 4096, 4096, 2048);
  k_gemm<true><<<dim3(32, 32), 256, 0, stream>>>(hsb, WgT, gb, 4096, 4096, 2048);
  k_rope<<<16384, 256, 0, stream>>>(qb, 0.0625f);
  k_rope<<<16384, 256, 0, stream>>>(kb, 1.0f);
  k_transpose_v<<<dim3(Tn / 32, DVv / 32, Bn * NH), tb, 0, stream>>>(vb, vTb);
  k_transpose_w<<<dim3(HID / 32, NH * DVv / 32), tb, 0, stream>>>(Wo, WoT, NH * DVv, HID);
  k_retention<<<dim3(Tn / 32, NH, Bn), 256, 0, stream>>>(qb, kb, vTb, gb, gnw, Xb);
  k_gemm<false><<<dim3(16, 32), 256, 0, stream>>>(Xb, WoT, out, 4096, 2048, 4096);
}

// Round 3
// 774.305 us; speedup vs baseline: 1.8884x; 1.1275x over previous
//
#include <hip/hip_runtime.h>
#include <hip/hip_bf16.h>
#include <math.h>

#define NH 8
#define DKk 256
#define DVv 512
#define Bn 2
#define Tn 2048
#define HID 2048
#define EPSf 1e-5f

typedef __bf16 bf16x8 __attribute__((ext_vector_type(8)));
typedef float f32x4 __attribute__((ext_vector_type(4)));
typedef unsigned short us8 __attribute__((ext_vector_type(8)));
using bf16 = __hip_bfloat16;
typedef unsigned short ushort_t;

__device__ __forceinline__ void gload_lds16(const void* g, void* lds_base) {
  __builtin_amdgcn_global_load_lds(
      (const __attribute__((address_space(1))) void*)g,
      (__attribute__((address_space(3))) void*)lds_base, 16, 0, 0);
}

__device__ __forceinline__ ushort_t f2bf_raw(float f) {
  bf16 h = __float2bfloat16(f);
  return *reinterpret_cast<ushort_t*>(&h);
}
__device__ __forceinline__ float bf2f_raw(ushort_t u) {
  union { unsigned int i; float f; } v; v.i = ((unsigned int)u) << 16; return v.f;
}

// ---------------- fp32 -> bf16 elementwise (vectorized x4) ----------------
__global__ void k_f32_to_bf16(const float4* __restrict__ in, ushort4* __restrict__ out, int n4) {
  int i = blockIdx.x * blockDim.x + threadIdx.x;
  if (i >= n4) return;
  float4 v = in[i];
  ushort4 o;
  o.x = f2bf_raw(v.x); o.y = f2bf_raw(v.y); o.z = f2bf_raw(v.z); o.w = f2bf_raw(v.w);
  out[i] = o;
}

// ---------------- W (K,N) fp32 -> WT (N,K) bf16 ----------------
__global__ void k_transpose_w(const float* __restrict__ W, bf16* __restrict__ WT, int K, int N) {
  __shared__ float t[32][33];
  int n0 = blockIdx.x * 32, k0 = blockIdx.y * 32;
  int tx = threadIdx.x, ty = threadIdx.y;
#pragma unroll
  for (int i = 0; i < 4; i++)
    t[ty + i * 8][tx] = W[(size_t)(k0 + ty + i * 8) * N + n0 + tx];
  __syncthreads();
#pragma unroll
  for (int i = 0; i < 4; i++)
    WT[(size_t)(n0 + ty + i * 8) * K + k0 + tx] = __float2bfloat16(t[tx][ty + i * 8]);
}

// ---------------- v (b,t,h,dv) bf16 -> vS[bh][kt][chunk(4)][dv(512)] 16B units ----------------
// vS unit (bh,kt,chunk,dv) holds v[dv][j = chunk*8 .. chunk*8+7] for tile kt (8 bf16 = 16B).
__global__ void k_build_vS(const ushort_t* __restrict__ v, ushort_t* __restrict__ vS) {
  __shared__ ushort_t t[32 * 520];  // row stride 520 ushorts (1040B): phase2 jj-stride = 4 banks
  const int tid = threadIdx.x;
  const int kt = blockIdx.x;
  const int bh = blockIdx.y;
  const int b = bh >> 3, h = bh & 7;
#pragma unroll
  for (int r = 0; r < 8; r++) {
    int j = r * 4 + (tid >> 6);
    int vec = tid & 63;
    us8 d = *(const us8*)(v + (((size_t)(b * Tn + kt * 32 + j) * NH + h) * DVv) + vec * 8);
    *(us8*)(&t[j * 520 + vec * 8]) = d;
  }
  __syncthreads();
#pragma unroll
  for (int u = 0; u < 8; u++) {
    int uid = u * 256 + tid;
    int chunk = uid >> 9;
    int dv = uid & 511;
    us8 o;
#pragma unroll
    for (int jj = 0; jj < 8; jj++) o[jj] = t[(chunk * 8 + jj) * 520 + dv];
    *(us8*)(vS + ((size_t)(bh * 64 + kt) * 2048 + chunk * 512 + dv) * 8) = o;
  }
}

// ---------------- RoPE in-place on bf16 (b,t,h,dk), scale folded ----------------
__global__ void k_rope(bf16* __restrict__ x, float scale) {
  int tid = blockIdx.x * 256 + threadIdx.x;
  int i = tid & 127;
  int h = (tid >> 7) & 7;
  int t = (tid >> 10) & (Tn - 1);
  int b = tid >> 21;
  float inv = exp2f(-(float)i * (13.287712379549449f / 128.0f));
  float ang = (float)t * inv;
  float s, c;
  sincosf(ang, &s, &c);
  size_t base = ((size_t)(b * Tn + t) * NH + h) * DKk + i;
  float x1 = __bfloat162float(x[base]);
  float x2 = __bfloat162float(x[base + 128]);
  x[base]       = __float2bfloat16((x1 * c - x2 * s) * scale);
  x[base + 128] = __float2bfloat16((x2 * c + x1 * s) * scale);
}

// ---------------- m97-style GEMM: C(M,N) = A(M,K) @ BT(N,K)^T ----------------
template <bool OUT_BF16>
__global__ __launch_bounds__(256) void k_gemm(const bf16* __restrict__ A, const bf16* __restrict__ BT,
                                              void* __restrict__ Cout, int M, int N, int K) {
  __shared__ __align__(16) bf16 a_lds[128 * 32];
  __shared__ __align__(16) bf16 b_lds[128 * 32];
  const int tid = threadIdx.x;
  const int l = tid & 63;
  const int w = tid >> 6;
  const int wr = w >> 1, wc = w & 1;
  const int m0 = blockIdx.y * 128, n0 = blockIdx.x * 128;
  const int quad = l >> 4, c16 = l & 15;

  const int lrow = l >> 2;
  const int loff = (l & 3) * 16;
  const char* aG0 = (const char*)(A + (size_t)(m0 + w * 32 + lrow) * K) + loff;
  const char* aG1 = (const char*)(A + (size_t)(m0 + w * 32 + 16 + lrow) * K) + loff;
  const char* bG0 = (const char*)(BT + (size_t)(n0 + w * 32 + lrow) * K) + loff;
  const char* bG1 = (const char*)(BT + (size_t)(n0 + w * 32 + 16 + lrow) * K) + loff;
  char* aL0 = (char*)a_lds + w * 2048;
  char* aL1 = (char*)a_lds + w * 2048 + 1024;
  char* bL0 = (char*)b_lds + w * 2048;
  char* bL1 = (char*)b_lds + w * 2048 + 1024;

  f32x4 acc[4][4];
  const f32x4 fz = {0.f, 0.f, 0.f, 0.f};
#pragma unroll
  for (int r = 0; r < 4; r++)
#pragma unroll
    for (int c = 0; c < 4; c++) acc[r][c] = fz;

  for (int k0 = 0; k0 < K; k0 += 32) {
    __syncthreads();
    size_t kb = (size_t)k0 * 2;
    gload_lds16(aG0 + kb, aL0);
    gload_lds16(aG1 + kb, aL1);
    gload_lds16(bG0 + kb, bL0);
    gload_lds16(bG1 + kb, bL1);
    __syncthreads();
    bf16x8 af[4], bfv[4];
#pragma unroll
    for (int r = 0; r < 4; r++)
      af[r] = *(const bf16x8*)(a_lds + (wr * 64 + r * 16 + c16) * 32 + quad * 8);
#pragma unroll
    for (int c = 0; c < 4; c++)
      bfv[c] = *(const bf16x8*)(b_lds + (wc * 64 + c * 16 + c16) * 32 + quad * 8);
#pragma unroll
    for (int r = 0; r < 4; r++)
#pragma unroll
      for (int c = 0; c < 4; c++)
        acc[r][c] = __builtin_amdgcn_mfma_f32_16x16x32_bf16(af[r], bfv[c], acc[r][c], 0, 0, 0);
  }

#pragma unroll
  for (int r = 0; r < 4; r++)
#pragma unroll
    for (int c = 0; c < 4; c++)
#pragma unroll
      for (int rr = 0; rr < 4; rr++) {
        int m = m0 + wr * 64 + r * 16 + quad * 4 + rr;
        int n = n0 + wc * 64 + c * 16 + c16;
        float val = acc[r][c][rr];
        if (OUT_BF16) ((bf16*)Cout)[(size_t)m * N + n] = __float2bfloat16(val);
        else          ((float*)Cout)[(size_t)m * N + n] = val;
      }
}

// ---------------- Retention: 64-row Q tile, 4 waves ----------------
// QK: wave w owns S rows w*16..w*16+15 (vs 32 j per step).
// PV: wave w owns dv slice w*128..w*128+127 for ALL 64 rows -> acc[4][8].
// vS: pre-swizzled [bh][kt][chunk][dv]. XCD-aware 1D grid: xcd = bid&7 pins head.
__global__ __launch_bounds__(256, 2) void k_retention(const bf16* __restrict__ q, const bf16* __restrict__ k,
                                                      const char* __restrict__ vS, const bf16* __restrict__ g,
                                                      const float* __restrict__ gnw, bf16* __restrict__ X) {
  __shared__ __align__(16) char smem[65536];
  bf16* k_lds = (bf16*)smem;               // [32 j][512B], XOR-swizzled chunks = 16KB
  char* v_lds = smem + 16384;              // [4 chunk][512 dv]x16B = 32KB
  ushort_t* p_lds = (ushort_t*)(smem + 49152);  // [64 rows] stride 40 ushorts (80B) = 5120B
  float* red = (float*)(smem + 54272);     // [64][4] = 1KB
  bf16* o_lds = (bf16*)smem;               // [64][512] = 64KB (epilogue, aliases everything)

  const int tid = threadIdx.x;
  const int l = tid & 63, w = tid >> 6;
  const int quad = l >> 4, c16 = l & 15;

  const int bid = blockIdx.x;
  const int xcd = bid & 7;
  const int slot = bid >> 3;
  const int bh = xcd + 8 * (slot & 1);
  const int b = bh >> 3, h = bh & 7;
  const int qt = 31 - (slot >> 1);        // longest blocks first
  const int q0 = qt * 64;

  // q fragments: wave w owns S rows q0 + w*16 + c16. A[m=c16][k=quad*8+j]
  bf16x8 qf[8];
  {
    const bf16* qrow = q + ((size_t)(b * Tn + q0 + w * 16 + c16) * NH + h) * DKk + quad * 8;
#pragma unroll
    for (int c = 0; c < 8; c++) qf[c] = *(const bf16x8*)(qrow + c * 32);
  }

  const float log2g = log2f(1.0f - exp2f(-5.0f - (float)h));

  f32x4 acc[4][8];
  const f32x4 fz = {0.f, 0.f, 0.f, 0.f};
#pragma unroll
  for (int rt = 0; rt < 4; rt++)
#pragma unroll
    for (int n = 0; n < 8; n++) acc[rt][n] = fz;

  const int ktmax = 2 * qt + 1;  // inclusive
  const float Dcut = 30.0f / (-log2g);
  int kt0 = (int)fmaxf(0.0f, floorf(((float)q0 - Dcut) * (1.0f / 32.0f)));

  const char* vS_tilebase = vS + (size_t)(bh * 64) * 32768;

  for (int kt = kt0; kt <= ktmax; kt++) {
    __syncthreads();
    // stage k tile: 16 instrs (4/wave); instr = 2 j-rows x 512B, 16B-chunk XOR swizzle
#pragma unroll
    for (int i = 0; i < 4; i++) {
      int instr = w * 4 + i;
      int j = instr * 2 + (l >> 5);
      int chunk_g = (l & 31) ^ (j & 7);
      const char* gp = (const char*)(k + ((size_t)(b * Tn + kt * 32 + j) * NH + h) * DKk) + chunk_g * 16;
      gload_lds16(gp, (char*)k_lds + instr * 1024);
    }
    // stage vS tile: 32 instrs (8/wave), fully contiguous 1KB each
#pragma unroll
    for (int i = 0; i < 8; i++) {
      int instr = w * 8 + i;
      const char* gp = vS_tilebase + (size_t)kt * 32768 + instr * 1024 + l * 16;
      gload_lds16(gp, v_lds + instr * 1024);
    }
    __syncthreads();

    // S: wave's 16 rows x 32 j (2 j-tiles)
    f32x4 sacc[2] = {fz, fz};
#pragma unroll
    for (int jt = 0; jt < 2; jt++)
#pragma unroll
      for (int c = 0; c < 8; c++) {
        const char* kp = (const char*)k_lds + (jt * 16 + c16) * 512 + (((c * 4 + quad) ^ (c16 & 7)) * 16);
        bf16x8 bfrag = *(const bf16x8*)kp;
        sacc[jt] = __builtin_amdgcn_mfma_f32_16x16x32_bf16(qf[c], bfrag, sacc[jt], 0, 0, 0);
      }

    // decay + causal mask -> P (bf16) in padded LDS
#pragma unroll
    for (int jt = 0; jt < 2; jt++)
#pragma unroll
      for (int r = 0; r < 4; r++) {
        int ig = q0 + w * 16 + quad * 4 + r;
        int jg = kt * 32 + jt * 16 + c16;
        int d = ig - jg;
        float val = (d >= 0) ? sacc[jt][r] * exp2f(log2g * (float)d) : 0.0f;
        p_lds[(w * 16 + quad * 4 + r) * 40 + jt * 16 + c16] = f2bf_raw(val);
      }
    __syncthreads();

    // O += P @ V : wave w covers dv = w*128..+127 for all 4 row-tiles
    bf16x8 pa[4];
#pragma unroll
    for (int rt = 0; rt < 4; rt++)
      pa[rt] = *(const bf16x8*)((const char*)p_lds + (rt * 16 + c16) * 80 + quad * 16);
#pragma unroll
    for (int n = 0; n < 8; n++) {
      bf16x8 bv = *(const bf16x8*)(v_lds + quad * 8192 + (w * 128 + n * 16 + c16) * 16);
#pragma unroll
      for (int rt = 0; rt < 4; rt++)
        acc[rt][n] = __builtin_amdgcn_mfma_f32_16x16x32_bf16(pa[rt], bv, acc[rt][n], 0, 0, 0);
    }
  }

  // RMS: wave has 128-dv partial for all 64 rows -> cross-wave combine via red
  __syncthreads();
#pragma unroll
  for (int rt = 0; rt < 4; rt++)
#pragma unroll
    for (int r = 0; r < 4; r++) {
      float s = 0.f;
#pragma unroll
      for (int n = 0; n < 8; n++) { float v = acc[rt][n][r]; s += v * v; }
      s += __shfl_xor(s, 1);
      s += __shfl_xor(s, 2);
      s += __shfl_xor(s, 4);
      s += __shfl_xor(s, 8);
      if (c16 == 0) red[(rt * 16 + quad * 4 + r) * 4 + w] = s;
    }
  __syncthreads();
  float ss[4][4];
#pragma unroll
  for (int rt = 0; rt < 4; rt++)
#pragma unroll
    for (int r = 0; r < 4; r++) {
      int row = rt * 16 + quad * 4 + r;
      float tot = red[row * 4] + red[row * 4 + 1] + red[row * 4 + 2] + red[row * 4 + 3];
      ss[rt][r] = rsqrtf(tot * (1.0f / DVv) + EPSf);
    }
  __syncthreads();

  // write normalized o (rms * gnw applied) to o_lds [64][512]
#pragma unroll
  for (int n = 0; n < 8; n++) {
    int col = w * 128 + n * 16 + c16;
    float gw = gnw[col];
#pragma unroll
    for (int rt = 0; rt < 4; rt++)
#pragma unroll
      for (int r = 0; r < 4; r++) {
        int row = rt * 16 + quad * 4 + r;
        o_lds[row * 512 + col] = __float2bfloat16(acc[rt][n][r] * ss[rt][r] * gw);
      }
  }
  __syncthreads();

  // store: gate with silu(g) read directly from global (coalesced ushort8)
#pragma unroll
  for (int it = 0; it < 16; it++) {
    int cid = it * 256 + tid;          // 4096 chunks of 16B
    int row = cid >> 6;
    int cp = (cid & 63) * 8;
    const ushort_t* gp = (const ushort_t*)g + ((size_t)(b * Tn + q0 + row) * NH + h) * DVv + cp;
    us8 gv = *(const us8*)gp;
    us8 ov;
#pragma unroll
    for (int e = 0; e < 8; e++) {
      float gf = bf2f_raw(gv[e]);
      float gate = gf / (1.0f + expf(-gf));
      float of = __bfloat162float(o_lds[row * 512 + cp + e]);
      ov[e] = f2bf_raw(of * gate);
    }
    *(us8*)((ushort_t*)X + ((size_t)(b * Tn + q0 + row) * NH + h) * DVv + cp) = ov;
  }
}

extern "C" void kernel_launch(void* const* d_in, const int* in_sizes, int n_in,
                              void* d_out, int out_size, void* d_ws, size_t ws_size,
                              hipStream_t stream) {
  const float* hs  = (const float*)d_in[0];
  const float* Wq  = (const float*)d_in[1];
  const float* Wk  = (const float*)d_in[2];
  const float* Wv  = (const float*)d_in[3];
  const float* Wg  = (const float*)d_in[4];
  const float* Wo  = (const float*)d_in[5];
  const float* gnw = (const float*)d_in[6];
  float* out = (float*)d_out;
  char* ws = (char*)d_ws;

  bf16* hsb = (bf16*)(ws);                    // 16 MB
  bf16* WqT = (bf16*)(ws + 16777216);         //  8 MB
  bf16* WkT = (bf16*)(ws + 25165824);         //  8 MB
  bf16* WvT = (bf16*)(ws + 33554432);         // 16 MB
  bf16* WgT = (bf16*)(ws + 50331648);         // 16 MB
  char* vSb = ws;                              // alias hsb/WqT/WkT (32 MB, dead after q/k/v GEMMs)
  bf16* WoT = (bf16*)(ws + 33554432);         // alias WvT (16 MB, dead after v GEMM)
  bf16* qb = (bf16*)(ws + 67108864);          // 16 MB
  bf16* kb = (bf16*)(ws + 83886080);          // 16 MB
  bf16* vb = (bf16*)(ws + 100663296);         // 32 MB
  bf16* gb = (bf16*)(ws + 134217728);         // 32 MB
  bf16* Xb = vb;                               // alias v (dead after vS build)

  dim3 tb(32, 8);

  k_f32_to_bf16<<<8192, 256, 0, stream>>>((const float4*)hs, (ushort4*)hsb, 2097152);
  k_transpose_w<<<dim3(HID / 32, HID / 32), tb, 0, stream>>>(Wq, WqT, HID, HID);
  k_transpose_w<<<dim3(HID / 32, HID / 32), tb, 0, stream>>>(Wk, WkT, HID, HID);
  k_transpose_w<<<dim3(NH * DVv / 32, HID / 32), tb, 0, stream>>>(Wv, WvT, HID, NH * DVv);
  k_transpose_w<<<dim3(NH * DVv / 32, HID / 32), tb, 0, stream>>>(Wg, WgT, HID, NH * DVv);
  k_gemm<true><<<dim3(16, 32), 256, 0, stream>>>(hsb, WqT, qb, 4096, 2048, 2048);
  k_gemm<true><<<dim3(16, 32), 256, 0, stream>>>(hsb, WkT, kb, 4096, 2048, 2048);
  k_gemm<true><<<dim3(32, 32), 256, 0, stream>>>(hsb, WvT, vb, 4096, 4096, 2048);
  k_gemm<true><<<dim3(32, 32), 256, 0, stream>>>(hsb, WgT, gb, 4096, 4096, 2048);
  k_rope<<<16384, 256, 0, stream>>>(qb, 0.0625f);
  k_rope<<<16384, 256, 0, stream>>>(kb, 1.0f);
  k_build_vS<<<dim3(64, 16), 256, 0, stream>>>((const ushort_t*)vb, (ushort_t*)vSb);
  k_transpose_w<<<dim3(HID / 32, NH * DVv / 32), tb, 0, stream>>>(Wo, WoT, NH * DVv, HID);
  k_retention<<<512, 256, 0, stream>>>(qb, kb, vSb, gb, gnw, Xb);
  k_gemm<false><<<dim3(16, 32), 256, 0, stream>>>(Xb, WoT, out, 4096, 2048, 4096);
}